// Round 1
// baseline (10759.079 us; speedup 1.0000x reference)
//
#include <hip/hip_runtime.h>
#include <hip/hip_bf16.h>
#include <stdint.h>

#define NN 100000   // nodes
#define DD 128      // input dim
#define OO 128      // output dim
#define NS 8        // relations
#define NB 4        // bases

typedef __attribute__((ext_vector_type(8))) short short8;
typedef __attribute__((ext_vector_type(4))) float f32x4;

__device__ __forceinline__ float bf2f(uint16_t u){
  union { uint32_t i; float f; } x; x.i = ((uint32_t)u) << 16; return x.f;
}
__device__ __forceinline__ uint16_t f2bf(float f){
  union { float f; uint32_t i; } x; x.f = f;
  uint32_t r = (x.i + 0x7FFFu + ((x.i >> 16) & 1u)) >> 16;  // RNE
  return (uint16_t)r;
}

// ---- cast features f32 -> bf16 (done once per call) ----
__global__ void cast_bf16_kernel(const float* __restrict__ in, uint16_t* __restrict__ out, int n4){
  int i = blockIdx.x * blockDim.x + threadIdx.x;
  if (i < n4){
    float4 v = ((const float4*)in)[i];
    ushort4 o;
    o.x = f2bf(v.x); o.y = f2bf(v.y); o.z = f2bf(v.z); o.w = f2bf(v.w);
    ((ushort4*)out)[i] = o;
  }
}

// ---- effective per-relation weight, TRANSPOSED: Vt[s][o][d] = M_s[d][o] ----
// M_s[d,o] = sum_b W_comp[d&7, b] * W[b*128 + s*16 + (d>>3), o]
// (this reproduces the reference's (D,S)->S*D reshape quirk exactly)
__global__ void vt_kernel(const float* __restrict__ W, const float* __restrict__ Wc,
                          uint16_t* __restrict__ Vt){
  int d  = threadIdx.x;        // 0..127
  int so = blockIdx.x;         // s*128 + o
  int s = so >> 7, o = so & 127;
  int wrow = s * 16 + (d >> 3);
  int wci  = (d & 7) * NB;
  float acc = 0.f;
#pragma unroll
  for (int b = 0; b < NB; ++b)
    acc += Wc[wci + b] * W[(b * DD + wrow) * OO + o];
  Vt[so * DD + d] = f2bf(acc);
}

// ---- H_s = X @ M_s  ([100000,128] @ [128,128], bf16 MFMA, fp32 accum) ----
// block = 256 threads (4 waves), each block does 64 rows x 128 cols, wave = 16 rows.
__global__ __launch_bounds__(256) void gemm_kernel(const uint16_t* __restrict__ X16,
                                                   const uint16_t* __restrict__ VtS,
                                                   uint16_t* __restrict__ H16){
  const int wave = threadIdx.x >> 6;
  const int lane = threadIdx.x & 63;
  const int lr = lane & 15, lk = lane >> 4;
  const int row0 = blockIdx.x * 64 + wave * 16;

  f32x4 acc[8];
#pragma unroll
  for (int t = 0; t < 8; ++t) acc[t] = (f32x4){0.f, 0.f, 0.f, 0.f};

  int arow = row0 + lr; if (arow >= NN) arow = NN - 1;   // clamp (stores are guarded)
  const uint16_t* aptr = X16 + (size_t)arow * DD + lk * 8;

#pragma unroll
  for (int kb = 0; kb < DD; kb += 32){
    short8 a = *(const short8*)(aptr + kb);              // A[row, kb + lk*8 + j]
#pragma unroll
    for (int t = 0; t < 8; ++t){
      // B[k, col] with col = t*16+lr, k = kb + lk*8 + j; Vt is [o][k] so contiguous
      short8 b = *(const short8*)(VtS + (size_t)(t * 16 + lr) * DD + kb + lk * 8);
      acc[t] = __builtin_amdgcn_mfma_f32_16x16x32_bf16(a, b, acc[t], 0, 0, 0);
    }
  }
  // C/D layout: col = lane&15, row = (lane>>4)*4 + reg   [measured: learn_hip m89]
#pragma unroll
  for (int t = 0; t < 8; ++t){
#pragma unroll
    for (int j = 0; j < 4; ++j){
      int r = row0 + lk * 4 + j;
      if (r < NN) H16[(size_t)r * OO + t * 16 + lr] = f2bf(acc[t][j]);
    }
  }
}

// ---- SpMM scatter: out[row] += val * H_s[col]  (f32 hardware atomics) ----
// one wave handles 64-edge batches: coalesced index loads, readlane broadcast,
// 256B coalesced gather of H row, 2 atomics per lane per edge.
__global__ __launch_bounds__(256) void spmm_kernel(const int* __restrict__ rows,
                                                   const int* __restrict__ cols,
                                                   const float* __restrict__ vals,
                                                   const uint16_t* __restrict__ H16,
                                                   float* __restrict__ out, int E){
  const int lane = threadIdx.x & 63;
  const int gwave = (int)((blockIdx.x * blockDim.x + threadIdx.x) >> 6);
  const int nw = (gridDim.x * blockDim.x) >> 6;
  for (int base = gwave * 64; base < E; base += nw * 64){
    int cnt = E - base; if (cnt > 64) cnt = 64;
    int r = 0, c = 0; float v = 0.f;
    if (lane < cnt){
      r = rows[base + lane]; c = cols[base + lane]; v = vals[base + lane];
    }
    for (int k = 0; k < cnt; ++k){
      int rr = __shfl(r, k);
      int cc = __shfl(c, k);
      float vv = __shfl(v, k);
      uint32_t pair = *(const uint32_t*)(H16 + (size_t)cc * OO + lane * 2);
      float f0 = bf2f((uint16_t)(pair & 0xFFFFu));
      float f1 = bf2f((uint16_t)(pair >> 16));
      float* dst = out + (size_t)rr * OO + lane * 2;
      unsafeAtomicAdd(dst,     vv * f0);
      unsafeAtomicAdd(dst + 1, vv * f1);
    }
  }
}

__global__ void relu_kernel(float* __restrict__ out, int n4){
  int i = blockIdx.x * blockDim.x + threadIdx.x;
  if (i < n4){
    float4 v = ((float4*)out)[i];
    v.x = fmaxf(v.x, 0.f); v.y = fmaxf(v.y, 0.f);
    v.z = fmaxf(v.z, 0.f); v.w = fmaxf(v.w, 0.f);
    ((float4*)out)[i] = v;
  }
}

extern "C" void kernel_launch(void* const* d_in, const int* in_sizes, int n_in,
                              void* d_out, int out_size, void* d_ws, size_t ws_size,
                              hipStream_t stream){
  const float* features = (const float*)d_in[0];
  const int*   rows     = (const int*)d_in[1];
  const int*   cols     = (const int*)d_in[2];
  const float* vals     = (const float*)d_in[3];
  const float* W        = (const float*)d_in[4];
  const float* Wc       = (const float*)d_in[5];
  float* out = (float*)d_out;
  const int E = in_sizes[1] / NS;

  char* ws = (char*)d_ws;
  uint16_t* X16 = (uint16_t*)ws;                              // 25,600,000 B
  uint16_t* Vt  = (uint16_t*)(ws + 25600000);                 //    262,144 B
  uint16_t* H16 = (uint16_t*)(ws + 25600000 + 262144);        // 25,600,000 B

  hipMemsetAsync(d_out, 0, (size_t)out_size * sizeof(float), stream);
  cast_bf16_kernel<<<(NN * DD / 4 + 255) / 256, 256, 0, stream>>>(features, X16, NN * DD / 4);
  vt_kernel<<<NS * OO, DD, 0, stream>>>(W, Wc, Vt);
  for (int s = 0; s < NS; ++s){
    gemm_kernel<<<(NN + 63) / 64, 256, 0, stream>>>(X16, Vt + (size_t)s * DD * OO, H16);
    spmm_kernel<<<4096, 256, 0, stream>>>(rows + (size_t)s * E, cols + (size_t)s * E,
                                          vals + (size_t)s * E, H16, out, E);
  }
  relu_kernel<<<(NN * OO / 4 + 255) / 256, 256, 0, stream>>>(out, NN * OO / 4);
}

// Round 2
// 1911.245 us; speedup vs baseline: 5.6294x; 5.6294x over previous
//
#include <hip/hip_runtime.h>
#include <hip/hip_bf16.h>
#include <stdint.h>

#define NN 100000   // nodes
#define DD 128      // input dim
#define OO 128      // output dim
#define NS 8        // relations
#define NB 4        // bases
#define CAP 48      // per-row edge bucket capacity (Poisson(16) tail @48 ~ 3.5e-11/row)

typedef __attribute__((ext_vector_type(8))) short short8;
typedef __attribute__((ext_vector_type(4))) float f32x4;

__device__ __forceinline__ float bf2f(uint16_t u){
  union { uint32_t i; float f; } x; x.i = ((uint32_t)u) << 16; return x.f;
}
__device__ __forceinline__ uint16_t f2bf(float f){
  union { float f; uint32_t i; } x; x.f = f;
  uint32_t r = (x.i + 0x7FFFu + ((x.i >> 16) & 1u)) >> 16;  // RNE
  return (uint16_t)r;
}

// ---- cast features f32 -> bf16 ----
__global__ void cast_bf16_kernel(const float* __restrict__ in, uint16_t* __restrict__ out, int n4){
  int i = blockIdx.x * blockDim.x + threadIdx.x;
  if (i < n4){
    float4 v = ((const float4*)in)[i];
    ushort4 o;
    o.x = f2bf(v.x); o.y = f2bf(v.y); o.z = f2bf(v.z); o.w = f2bf(v.w);
    ((ushort4*)out)[i] = o;
  }
}

// ---- effective per-relation weight, TRANSPOSED: Vt[s][o][d] = M_s[d][o] ----
// M_s[d,o] = sum_b W_comp[d&7, b] * W[b*128 + s*16 + (d>>3), o]
// (reproduces the reference's (D,S)->S*D reshape quirk exactly; validated R0)
__global__ void vt_kernel(const float* __restrict__ W, const float* __restrict__ Wc,
                          uint16_t* __restrict__ Vt){
  int d  = threadIdx.x;        // 0..127
  int so = blockIdx.x;         // s*128 + o
  int s = so >> 7, o = so & 127;
  int wrow = s * 16 + (d >> 3);
  int wci  = (d & 7) * NB;
  float acc = 0.f;
#pragma unroll
  for (int b = 0; b < NB; ++b)
    acc += Wc[wci + b] * W[(b * DD + wrow) * OO + o];
  Vt[so * DD + d] = f2bf(acc);
}

// ---- H_s = X @ M_s  ([100000,128] @ [128,128], bf16 MFMA, fp32 accum) ----
__global__ __launch_bounds__(256) void gemm_kernel(const uint16_t* __restrict__ X16,
                                                   const uint16_t* __restrict__ VtS,
                                                   uint16_t* __restrict__ H16){
  const int wave = threadIdx.x >> 6;
  const int lane = threadIdx.x & 63;
  const int lr = lane & 15, lk = lane >> 4;
  const int row0 = blockIdx.x * 64 + wave * 16;

  f32x4 acc[8];
#pragma unroll
  for (int t = 0; t < 8; ++t) acc[t] = (f32x4){0.f, 0.f, 0.f, 0.f};

  int arow = row0 + lr; if (arow >= NN) arow = NN - 1;   // clamp (stores guarded)
  const uint16_t* aptr = X16 + (size_t)arow * DD + lk * 8;

#pragma unroll
  for (int kb = 0; kb < DD; kb += 32){
    short8 a = *(const short8*)(aptr + kb);
#pragma unroll
    for (int t = 0; t < 8; ++t){
      short8 b = *(const short8*)(VtS + (size_t)(t * 16 + lr) * DD + kb + lk * 8);
      acc[t] = __builtin_amdgcn_mfma_f32_16x16x32_bf16(a, b, acc[t], 0, 0, 0);
    }
  }
#pragma unroll
  for (int t = 0; t < 8; ++t){
#pragma unroll
    for (int j = 0; j < 4; ++j){
      int r = row0 + lk * 4 + j;
      if (r < NN) H16[(size_t)r * OO + t * 16 + lr] = f2bf(acc[t][j]);
    }
  }
}

// ---- scatter edges into per-row buckets: payload[row*CAP + pos] = {col, val} ----
// overflow (pos >= CAP, ~never) falls back to direct atomics into out (H ready).
__global__ __launch_bounds__(256) void scatter_kernel(const int* __restrict__ rows,
                                                      const int* __restrict__ cols,
                                                      const float* __restrict__ vals,
                                                      const uint16_t* __restrict__ H16,
                                                      int* __restrict__ cnt,
                                                      int2* __restrict__ payload,
                                                      float* __restrict__ out, int E){
  int e = blockIdx.x * blockDim.x + threadIdx.x;
  if (e >= E) return;
  int r = rows[e], c = cols[e];
  float v = vals[e];
  int pos = atomicAdd(&cnt[r], 1);
  if (pos < CAP){
    payload[(size_t)r * CAP + pos] = make_int2(c, __float_as_int(v));
  } else {
    const uint16_t* h = H16 + (size_t)c * OO;
    float* dst = out + (size_t)r * OO;
    for (int d = 0; d < OO; ++d) unsafeAtomicAdd(dst + d, v * bf2f(h[d]));
  }
}

// ---- gather: one wave per output row; out[row] += sum val * H[col]  (no atomics) ----
__global__ __launch_bounds__(256) void gather_kernel(const int* __restrict__ cnt,
                                                     const int2* __restrict__ payload,
                                                     const uint16_t* __restrict__ H16,
                                                     float* __restrict__ out){
  const int lane = threadIdx.x & 63;
  const int row  = blockIdx.x * 4 + (threadIdx.x >> 6);
  if (row >= NN) return;
  int deg = cnt[row]; if (deg > CAP) deg = CAP;

  float2 acc = *(const float2*)(out + (size_t)row * OO + lane * 2);
  int2 p = make_int2(0, 0);
  if (lane < deg) p = payload[(size_t)row * CAP + lane];

  for (int k = 0; k < deg; ++k){
    int   cc = __builtin_amdgcn_readlane(p.x, k);
    float vv = __int_as_float(__builtin_amdgcn_readlane(p.y, k));
    uint32_t pair = *(const uint32_t*)(H16 + (size_t)cc * OO + lane * 2);
    acc.x += vv * bf2f((uint16_t)(pair & 0xFFFFu));
    acc.y += vv * bf2f((uint16_t)(pair >> 16));
  }
  *(float2*)(out + (size_t)row * OO + lane * 2) = acc;
}

// ---- fallback atomic spmm (R0 path, used only if ws too small) ----
__global__ __launch_bounds__(256) void spmm_kernel(const int* __restrict__ rows,
                                                   const int* __restrict__ cols,
                                                   const float* __restrict__ vals,
                                                   const uint16_t* __restrict__ H16,
                                                   float* __restrict__ out, int E){
  const int lane = threadIdx.x & 63;
  const int gwave = (int)((blockIdx.x * blockDim.x + threadIdx.x) >> 6);
  const int nw = (gridDim.x * blockDim.x) >> 6;
  for (int base = gwave * 64; base < E; base += nw * 64){
    int cnt = E - base; if (cnt > 64) cnt = 64;
    int r = 0, c = 0; float v = 0.f;
    if (lane < cnt){
      r = rows[base + lane]; c = cols[base + lane]; v = vals[base + lane];
    }
    for (int k = 0; k < cnt; ++k){
      int rr = __shfl(r, k);
      int cc = __shfl(c, k);
      float vv = __shfl(v, k);
      uint32_t pair = *(const uint32_t*)(H16 + (size_t)cc * OO + lane * 2);
      float* dst = out + (size_t)rr * OO + lane * 2;
      unsafeAtomicAdd(dst,     vv * bf2f((uint16_t)(pair & 0xFFFFu)));
      unsafeAtomicAdd(dst + 1, vv * bf2f((uint16_t)(pair >> 16)));
    }
  }
}

__global__ void relu_kernel(float* __restrict__ out, int n4){
  int i = blockIdx.x * blockDim.x + threadIdx.x;
  if (i < n4){
    float4 v = ((float4*)out)[i];
    v.x = fmaxf(v.x, 0.f); v.y = fmaxf(v.y, 0.f);
    v.z = fmaxf(v.z, 0.f); v.w = fmaxf(v.w, 0.f);
    ((float4*)out)[i] = v;
  }
}

extern "C" void kernel_launch(void* const* d_in, const int* in_sizes, int n_in,
                              void* d_out, int out_size, void* d_ws, size_t ws_size,
                              hipStream_t stream){
  const float* features = (const float*)d_in[0];
  const int*   rows     = (const int*)d_in[1];
  const int*   cols     = (const int*)d_in[2];
  const float* vals     = (const float*)d_in[3];
  const float* W        = (const float*)d_in[4];
  const float* Wc       = (const float*)d_in[5];
  float* out = (float*)d_out;
  const int E = in_sizes[1] / NS;

  char* ws = (char*)d_ws;
  uint16_t* X16 = (uint16_t*)ws;                               // 25,600,000 B
  uint16_t* Vt  = (uint16_t*)(ws + 25600000);                  //    262,144 B
  uint16_t* H16 = (uint16_t*)(ws + 25862144);                  // 25,600,000 B
  int*      cnt = (int*)     (ws + 51462144);                  //    400,000 B
  int2*     pay = (int2*)    (ws + 51862144);                  // 38,400,000 B
  const size_t NEEDED = 51862144 + (size_t)NN * CAP * 8;       // ~90.3 MB

  hipMemsetAsync(d_out, 0, (size_t)out_size * sizeof(float), stream);
  cast_bf16_kernel<<<(NN * DD / 4 + 255) / 256, 256, 0, stream>>>(features, X16, NN * DD / 4);
  vt_kernel<<<NS * OO, DD, 0, stream>>>(W, Wc, Vt);

  if (ws_size >= NEEDED){
    for (int s = 0; s < NS; ++s){
      gemm_kernel<<<(NN + 63) / 64, 256, 0, stream>>>(X16, Vt + (size_t)s * DD * OO, H16);
      hipMemsetAsync(cnt, 0, (size_t)NN * sizeof(int), stream);
      scatter_kernel<<<(E + 255) / 256, 256, 0, stream>>>(rows + (size_t)s * E, cols + (size_t)s * E,
                                                          vals + (size_t)s * E, H16, cnt, pay, out, E);
      gather_kernel<<<(NN + 3) / 4, 256, 0, stream>>>(cnt, pay, H16, out);
    }
  } else {
    for (int s = 0; s < NS; ++s){
      gemm_kernel<<<(NN + 63) / 64, 256, 0, stream>>>(X16, Vt + (size_t)s * DD * OO, H16);
      spmm_kernel<<<4096, 256, 0, stream>>>(rows + (size_t)s * E, cols + (size_t)s * E,
                                            vals + (size_t)s * E, H16, out, E);
    }
  }
  relu_kernel<<<(NN * OO / 4 + 255) / 256, 256, 0, stream>>>(out, NN * OO / 4);
}

// Round 3
// 1897.109 us; speedup vs baseline: 5.6713x; 1.0075x over previous
//
#include <hip/hip_runtime.h>
#include <hip/hip_bf16.h>
#include <stdint.h>

#define NN 100000   // nodes
#define DD 128      // input dim
#define OO 128      // output dim
#define NS 8        // relations
#define NB 4        // bases
#define CAP4 32     // main path: per-row per-relation bucket capacity (Poisson(16) tail @32 ~ 7e-5)
#define CAPF 48     // fallback path capacity (R2-validated)

typedef __attribute__((ext_vector_type(8))) short short8;
typedef __attribute__((ext_vector_type(4))) float f32x4;

__device__ __forceinline__ float bf2f(uint16_t u){
  union { uint32_t i; float f; } x; x.i = ((uint32_t)u) << 16; return x.f;
}
__device__ __forceinline__ uint16_t f2bf(float f){
  union { float f; uint32_t i; } x; x.f = f;
  uint32_t r = (x.i + 0x7FFFu + ((x.i >> 16) & 1u)) >> 16;  // RNE
  return (uint16_t)r;
}

// ---- effective per-relation weight, TRANSPOSED: Vt[s][o][d] = M_s[d][o] ----
// M_s[d,o] = sum_b W_comp[d&7, b] * W[b*128 + s*16 + (d>>3), o]
// (reproduces the reference's (D,S)->S*D reshape quirk; validated R1/R2)
__global__ void vt_kernel(const float* __restrict__ W, const float* __restrict__ Wc,
                          uint16_t* __restrict__ Vt){
  int d  = threadIdx.x;        // 0..127
  int so = blockIdx.x;         // s*128 + o
  int s = so >> 7, o = so & 127;
  int wrow = s * 16 + (d >> 3);
  int wci  = (d & 7) * NB;
  float acc = 0.f;
#pragma unroll
  for (int b = 0; b < NB; ++b)
    acc += Wc[wci + b] * W[(b * DD + wrow) * OO + o];
  Vt[so * DD + d] = f2bf(acc);
}

// ---- fused: H_s = X @ M_s for ALL s, reading f32 features once (cast in-reg) ----
__global__ __launch_bounds__(256) void gemm_all_kernel(const float* __restrict__ X,
                                                       const uint16_t* __restrict__ Vt,
                                                       uint16_t* __restrict__ Hall){
  const int wave = threadIdx.x >> 6;
  const int lane = threadIdx.x & 63;
  const int lr = lane & 15, lk = lane >> 4;
  const int row0 = blockIdx.x * 64 + wave * 16;

  int arow = row0 + lr; if (arow >= NN) arow = NN - 1;   // clamp (stores guarded)
  const float* ap = X + (size_t)arow * DD;
  short8 a[4];
#pragma unroll
  for (int kb = 0; kb < 4; ++kb){
    float4 f0 = *(const float4*)(ap + kb * 32 + lk * 8);
    float4 f1 = *(const float4*)(ap + kb * 32 + lk * 8 + 4);
    short8 t;
    t[0] = (short)f2bf(f0.x); t[1] = (short)f2bf(f0.y);
    t[2] = (short)f2bf(f0.z); t[3] = (short)f2bf(f0.w);
    t[4] = (short)f2bf(f1.x); t[5] = (short)f2bf(f1.y);
    t[6] = (short)f2bf(f1.z); t[7] = (short)f2bf(f1.w);
    a[kb] = t;
  }

  for (int s = 0; s < NS; ++s){
    f32x4 acc[8];
#pragma unroll
    for (int t = 0; t < 8; ++t) acc[t] = (f32x4){0.f, 0.f, 0.f, 0.f};
    const uint16_t* vb = Vt + (size_t)s * OO * DD;
#pragma unroll
    for (int kb = 0; kb < 4; ++kb){
#pragma unroll
      for (int t = 0; t < 8; ++t){
        short8 b = *(const short8*)(vb + (size_t)(t * 16 + lr) * DD + kb * 32 + lk * 8);
        acc[t] = __builtin_amdgcn_mfma_f32_16x16x32_bf16(a[kb], b, acc[t], 0, 0, 0);
      }
    }
    uint16_t* hs = Hall + (size_t)s * NN * OO;
    // C/D layout: col = lane&15, row = (lane>>4)*4 + reg   [learn_hip m89]
#pragma unroll
    for (int t = 0; t < 8; ++t){
#pragma unroll
      for (int j = 0; j < 4; ++j){
        int r = row0 + lk * 4 + j;
        if (r < NN) hs[(size_t)r * OO + t * 16 + lr] = f2bf(acc[t][j]);
      }
    }
  }
}

__device__ __noinline__ void overflow_add(int r, int c, float v,
                                          const uint16_t* __restrict__ H16,
                                          float* __restrict__ out){
  const uint16_t* h = H16 + (size_t)c * OO;
  float* dst = out + (size_t)r * OO;
  for (int d = 0; d < OO; ++d) unsafeAtomicAdd(dst + d, v * bf2f(h[d]));
}

// ---- scatter with 4-edge ILP: 4 independent atomic+store chains per thread ----
__global__ __launch_bounds__(256) void scatter_ilp_kernel(const int* __restrict__ rows,
                                                          const int* __restrict__ cols,
                                                          const float* __restrict__ vals,
                                                          const uint16_t* __restrict__ H16,
                                                          int* __restrict__ cnt,
                                                          int2* __restrict__ pay,
                                                          float* __restrict__ out, int E){
  int t = blockIdx.x * blockDim.x + threadIdx.x;
  int e0 = t * 4;
  if (e0 >= E) return;
  if (e0 + 3 < E){
    int4   r4 = *(const int4*)(rows + e0);
    int4   c4 = *(const int4*)(cols + e0);
    float4 v4 = *(const float4*)(vals + e0);
    int p0 = atomicAdd(&cnt[r4.x], 1);
    int p1 = atomicAdd(&cnt[r4.y], 1);
    int p2 = atomicAdd(&cnt[r4.z], 1);
    int p3 = atomicAdd(&cnt[r4.w], 1);
    if (p0 < CAP4) pay[(size_t)r4.x * CAP4 + p0] = make_int2(c4.x, __float_as_int(v4.x));
    else overflow_add(r4.x, c4.x, v4.x, H16, out);
    if (p1 < CAP4) pay[(size_t)r4.y * CAP4 + p1] = make_int2(c4.y, __float_as_int(v4.y));
    else overflow_add(r4.y, c4.y, v4.y, H16, out);
    if (p2 < CAP4) pay[(size_t)r4.z * CAP4 + p2] = make_int2(c4.z, __float_as_int(v4.z));
    else overflow_add(r4.z, c4.z, v4.z, H16, out);
    if (p3 < CAP4) pay[(size_t)r4.w * CAP4 + p3] = make_int2(c4.w, __float_as_int(v4.w));
    else overflow_add(r4.w, c4.w, v4.w, H16, out);
  } else {
    for (int e = e0; e < E; ++e){
      int r = rows[e], c = cols[e];
      float v = vals[e];
      int pos = atomicAdd(&cnt[r], 1);
      if (pos < CAP4) pay[(size_t)r * CAP4 + pos] = make_int2(c, __float_as_int(v));
      else overflow_add(r, c, v, H16, out);
    }
  }
}

// ---- gather 4 relations per pass: one wave per row, out RMW once per pass ----
template<bool LAST>
__global__ __launch_bounds__(256) void gather4_kernel(const int* __restrict__ cnt4,
                                                      const int2* __restrict__ pay4,
                                                      const uint16_t* __restrict__ H4,
                                                      float* __restrict__ out){
  const int lane = threadIdx.x & 63;
  const int row  = blockIdx.x * 4 + (threadIdx.x >> 6);
  if (row >= NN) return;
  float2 acc = *(const float2*)(out + (size_t)row * OO + lane * 2);
#pragma unroll
  for (int s = 0; s < 4; ++s){
    int deg = cnt4[s * NN + row]; if (deg > CAP4) deg = CAP4;
    int2 p = make_int2(0, 0);
    if (lane < deg) p = pay4[((size_t)s * NN + row) * CAP4 + lane];
    const uint16_t* hs = H4 + (size_t)s * NN * OO;
    for (int k = 0; k < deg; ++k){
      int   cc = __builtin_amdgcn_readlane(p.x, k);
      float vv = __int_as_float(__builtin_amdgcn_readlane(p.y, k));
      uint32_t pair = *(const uint32_t*)(hs + (size_t)cc * OO + lane * 2);
      acc.x += vv * bf2f((uint16_t)(pair & 0xFFFFu));
      acc.y += vv * bf2f((uint16_t)(pair >> 16));
    }
  }
  if (LAST){ acc.x = fmaxf(acc.x, 0.f); acc.y = fmaxf(acc.y, 0.f); }
  *(float2*)(out + (size_t)row * OO + lane * 2) = acc;
}

// ======================= R2-validated fallback path =======================
__global__ void cast_bf16_kernel(const float* __restrict__ in, uint16_t* __restrict__ out, int n4){
  int i = blockIdx.x * blockDim.x + threadIdx.x;
  if (i < n4){
    float4 v = ((const float4*)in)[i];
    ushort4 o;
    o.x = f2bf(v.x); o.y = f2bf(v.y); o.z = f2bf(v.z); o.w = f2bf(v.w);
    ((ushort4*)out)[i] = o;
  }
}

__global__ __launch_bounds__(256) void gemm_kernel(const uint16_t* __restrict__ X16,
                                                   const uint16_t* __restrict__ VtS,
                                                   uint16_t* __restrict__ H16){
  const int wave = threadIdx.x >> 6;
  const int lane = threadIdx.x & 63;
  const int lr = lane & 15, lk = lane >> 4;
  const int row0 = blockIdx.x * 64 + wave * 16;
  f32x4 acc[8];
#pragma unroll
  for (int t = 0; t < 8; ++t) acc[t] = (f32x4){0.f, 0.f, 0.f, 0.f};
  int arow = row0 + lr; if (arow >= NN) arow = NN - 1;
  const uint16_t* aptr = X16 + (size_t)arow * DD + lk * 8;
#pragma unroll
  for (int kb = 0; kb < DD; kb += 32){
    short8 a = *(const short8*)(aptr + kb);
#pragma unroll
    for (int t = 0; t < 8; ++t){
      short8 b = *(const short8*)(VtS + (size_t)(t * 16 + lr) * DD + kb + lk * 8);
      acc[t] = __builtin_amdgcn_mfma_f32_16x16x32_bf16(a, b, acc[t], 0, 0, 0);
    }
  }
#pragma unroll
  for (int t = 0; t < 8; ++t){
#pragma unroll
    for (int j = 0; j < 4; ++j){
      int r = row0 + lk * 4 + j;
      if (r < NN) H16[(size_t)r * OO + t * 16 + lr] = f2bf(acc[t][j]);
    }
  }
}

__global__ __launch_bounds__(256) void scatter_kernel(const int* __restrict__ rows,
                                                      const int* __restrict__ cols,
                                                      const float* __restrict__ vals,
                                                      const uint16_t* __restrict__ H16,
                                                      int* __restrict__ cnt,
                                                      int2* __restrict__ payload,
                                                      float* __restrict__ out, int E){
  int e = blockIdx.x * blockDim.x + threadIdx.x;
  if (e >= E) return;
  int r = rows[e], c = cols[e];
  float v = vals[e];
  int pos = atomicAdd(&cnt[r], 1);
  if (pos < CAPF) payload[(size_t)r * CAPF + pos] = make_int2(c, __float_as_int(v));
  else overflow_add(r, c, v, H16, out);
}

__global__ __launch_bounds__(256) void gather_kernel(const int* __restrict__ cnt,
                                                     const int2* __restrict__ payload,
                                                     const uint16_t* __restrict__ H16,
                                                     float* __restrict__ out){
  const int lane = threadIdx.x & 63;
  const int row  = blockIdx.x * 4 + (threadIdx.x >> 6);
  if (row >= NN) return;
  int deg = cnt[row]; if (deg > CAPF) deg = CAPF;
  float2 acc = *(const float2*)(out + (size_t)row * OO + lane * 2);
  int2 p = make_int2(0, 0);
  if (lane < deg) p = payload[(size_t)row * CAPF + lane];
  for (int k = 0; k < deg; ++k){
    int   cc = __builtin_amdgcn_readlane(p.x, k);
    float vv = __int_as_float(__builtin_amdgcn_readlane(p.y, k));
    uint32_t pair = *(const uint32_t*)(H16 + (size_t)cc * OO + lane * 2);
    acc.x += vv * bf2f((uint16_t)(pair & 0xFFFFu));
    acc.y += vv * bf2f((uint16_t)(pair >> 16));
  }
  *(float2*)(out + (size_t)row * OO + lane * 2) = acc;
}

__global__ void relu_kernel(float* __restrict__ out, int n4){
  int i = blockIdx.x * blockDim.x + threadIdx.x;
  if (i < n4){
    float4 v = ((float4*)out)[i];
    v.x = fmaxf(v.x, 0.f); v.y = fmaxf(v.y, 0.f);
    v.z = fmaxf(v.z, 0.f); v.w = fmaxf(v.w, 0.f);
    ((float4*)out)[i] = v;
  }
}
// =========================================================================

extern "C" void kernel_launch(void* const* d_in, const int* in_sizes, int n_in,
                              void* d_out, int out_size, void* d_ws, size_t ws_size,
                              hipStream_t stream){
  const float* features = (const float*)d_in[0];
  const int*   rows     = (const int*)d_in[1];
  const int*   cols     = (const int*)d_in[2];
  const float* vals     = (const float*)d_in[3];
  const float* W        = (const float*)d_in[4];
  const float* Wc       = (const float*)d_in[5];
  float* out = (float*)d_out;
  const int E = in_sizes[1] / NS;

  char* ws = (char*)d_ws;

  // ---- main path layout ----
  uint16_t* VtM  = (uint16_t*)ws;                                  //      262,144
  uint16_t* Hall = (uint16_t*)(ws + 262144);                       //  204,800,000
  int*      cnt4 = (int*)     (ws + 262144 + 204800000);           //    1,600,000
  int2*     pay4 = (int2*)    (ws + 262144 + 204800000 + 1600000); //  102,400,000
  const size_t NEEDED_MAIN = 262144 + 204800000 + 1600000 + 102400000; // ~309 MB

  hipMemsetAsync(d_out, 0, (size_t)out_size * sizeof(float), stream);

  if (ws_size >= NEEDED_MAIN){
    vt_kernel<<<NS * OO, DD, 0, stream>>>(W, Wc, VtM);
    gemm_all_kernel<<<(NN + 63) / 64, 256, 0, stream>>>(features, VtM, Hall);
    for (int pass = 0; pass < 2; ++pass){
      hipMemsetAsync(cnt4, 0, (size_t)4 * NN * sizeof(int), stream);
      for (int i = 0; i < 4; ++i){
        int s = pass * 4 + i;
        scatter_ilp_kernel<<<(E + 1023) / 1024, 256, 0, stream>>>(
            rows + (size_t)s * E, cols + (size_t)s * E, vals + (size_t)s * E,
            Hall + (size_t)s * NN * OO, cnt4 + (size_t)i * NN,
            pay4 + (size_t)i * NN * CAP4, out, E);
      }
      const uint16_t* H4 = Hall + (size_t)pass * 4 * NN * OO;
      if (pass == 0)
        gather4_kernel<false><<<(NN + 3) / 4, 256, 0, stream>>>(cnt4, pay4, H4, out);
      else
        gather4_kernel<true><<<(NN + 3) / 4, 256, 0, stream>>>(cnt4, pay4, H4, out);
    }
    return;
  }

  // ---- fallback: R2-validated path ----
  uint16_t* X16 = (uint16_t*)ws;                               // 25,600,000
  uint16_t* Vt  = (uint16_t*)(ws + 25600000);                  //    262,144
  uint16_t* H16 = (uint16_t*)(ws + 25862144);                  // 25,600,000
  int*      cnt = (int*)     (ws + 51462144);                  //    400,000
  int2*     pay = (int2*)    (ws + 51862144);                  // 38,400,000
  const size_t NEEDED_F = 51862144 + (size_t)NN * CAPF * 8;

  cast_bf16_kernel<<<(NN * DD / 4 + 255) / 256, 256, 0, stream>>>(features, X16, NN * DD / 4);
  vt_kernel<<<NS * OO, DD, 0, stream>>>(W, Wc, Vt);
  if (ws_size >= NEEDED_F){
    for (int s = 0; s < NS; ++s){
      gemm_kernel<<<(NN + 63) / 64, 256, 0, stream>>>(X16, Vt + (size_t)s * DD * OO, H16);
      hipMemsetAsync(cnt, 0, (size_t)NN * sizeof(int), stream);
      scatter_kernel<<<(E + 255) / 256, 256, 0, stream>>>(rows + (size_t)s * E, cols + (size_t)s * E,
                                                          vals + (size_t)s * E, H16, cnt, pay, out, E);
      gather_kernel<<<(NN + 3) / 4, 256, 0, stream>>>(cnt, pay, H16, out);
    }
  } else {
    for (int s = 0; s < NS; ++s){
      gemm_kernel<<<(NN + 63) / 64, 256, 0, stream>>>(X16, Vt + (size_t)s * DD * OO, H16);
      // atomic fallback (R0): reuse scatter overflow path per edge
      scatter_kernel<<<(E + 255) / 256, 256, 0, stream>>>(rows + (size_t)s * E, cols + (size_t)s * E,
                                                          vals + (size_t)s * E, H16, cnt, pay, out, E);
    }
  }
  relu_kernel<<<(NN * OO / 4 + 255) / 256, 256, 0, stream>>>(out, NN * OO / 4);
}